// Round 2
// baseline (48201.700 us; speedup 1.0000x reference)
//
#include <hip/hip_runtime.h>
#include <float.h>

// TransitionDown: FPS -> kNN(16) -> Linear(64,128)+BN(train stats)+ReLU -> neighborhood max
#define N_PTS 32768
#define M_CL  8192
#define IN_C  64
#define OUT_C 128
#define K_NN  16
constexpr float BN_EPS_C = 1e-5f;

// ---------------- ws layout (bytes) ----------------
// 0        : posx [N] f32
// 131072   : posy [N]
// 262144   : posz [N]
// 393216   : ids  [M] int
// 425984   : nn   [M*16] int
// 950272   : psum   [512*128] f32
// 1212416  : psumsq [512*128] f32
// 1474560  : scale [128] f32
// 1475072  : shift [128] f32
// 2097152  : h [N*128] f32  (16 MiB)  -> end 18874368

// ---------------------------------------------------------------------------
// 0) AoS -> SoA for pos (coalescing for FPS/kNN)
__global__ void soa_kernel(const float* __restrict__ pos,
                           float* __restrict__ px, float* __restrict__ py, float* __restrict__ pz) {
    int i = blockIdx.x * 256 + threadIdx.x;
    if (i < N_PTS) {
        px[i] = pos[3 * i + 0];
        py[i] = pos[3 * i + 1];
        pz[i] = pos[3 * i + 2];
    }
}

// ---------------------------------------------------------------------------
// 1) Farthest-point sampling. Single block, 512 threads, 64 points/thread.
//    CRITICAL: distance arithmetic must be bit-identical to the jax f32
//    reference: unfused squares, sum as (xx+yy)+zz. fp contract OFF here.
//    (The absmax threshold is calibrated from jax-f32 vs np-f64, which agree
//    on every FPS argmax; any other f32 rounding pattern risks a flip that
//    cascades through all later selections.)
//    Tie-break: lowest index (np.argmax first-occurrence).
__global__ __launch_bounds__(512) void fps_kernel(
    const float* __restrict__ posx, const float* __restrict__ posy, const float* __restrict__ posz,
    const int* __restrict__ batch,
    int* __restrict__ ids, float* __restrict__ out_subpos, float* __restrict__ out_subbatch) {
    #pragma clang fp contract(off)
    __shared__ __align__(16) float md[N_PTS];      // 128 KiB
    __shared__ float rv[8];
    __shared__ int ri[8];
    __shared__ float4 selp;

    const int tid = threadIdx.x;
    float lx[64], ly[64], lz[64];
    #pragma unroll
    for (int c = 0; c < 16; ++c) {
        #pragma unroll
        for (int e = 0; e < 4; ++e) {
            int i = c * 2048 + (tid << 2) + e;
            int j = (c << 2) | e;
            lx[j] = posx[i]; ly[j] = posy[i]; lz[j] = posz[i];
        }
    }
    float sx = posx[0], sy = posy[0], sz = posz[0];
    if (tid == 0) {
        ids[0] = 0;
        out_subpos[0] = sx; out_subpos[1] = sy; out_subpos[2] = sz;
        out_subbatch[0] = (float)batch[0];
    }
    // init min_d = dist^2 to point 0; track per-thread (max, argmax)
    float lmax = -1.0f; int lidx = 0;
    #pragma unroll
    for (int c = 0; c < 16; ++c) {
        float4 nv;
        #pragma unroll
        for (int e = 0; e < 4; ++e) {
            int j = (c << 2) | e;
            int i = c * 2048 + (tid << 2) + e;
            float dx = lx[j] - sx;
            float dy = ly[j] - sy;
            float dz = lz[j] - sz;
            float xx = dx * dx;
            float yy = dy * dy;
            float zz = dz * dz;
            float d = (xx + yy) + zz;
            (&nv.x)[e] = d;
            if (d > lmax) { lmax = d; lidx = i; }
        }
        *reinterpret_cast<float4*>(&md[c * 2048 + (tid << 2)]) = nv;
    }

    for (int t = 1; t < M_CL; ++t) {
        // wave-level lex argmax (value desc, index asc)
        float v = lmax; int bi = lidx;
        #pragma unroll
        for (int off = 32; off; off >>= 1) {
            float ov = __shfl_xor(v, off);
            int oi = __shfl_xor(bi, off);
            if (ov > v || (ov == v && oi < bi)) { v = ov; bi = oi; }
        }
        if ((tid & 63) == 0) { rv[tid >> 6] = v; ri[tid >> 6] = bi; }
        __syncthreads();
        if (tid < 64) {
            float v2 = (tid < 8) ? rv[tid] : -2.0f;
            int i2 = (tid < 8) ? ri[tid] : 0x7fffffff;
            #pragma unroll
            for (int off = 4; off; off >>= 1) {
                float ov = __shfl_xor(v2, off);
                int oi = __shfl_xor(i2, off);
                if (ov > v2 || (ov == v2 && oi < i2)) { v2 = ov; i2 = oi; }
            }
            if (tid == 0) {
                float wx = posx[i2], wy = posy[i2], wz = posz[i2];
                selp = make_float4(wx, wy, wz, 0.0f);
                ids[t] = i2;
                out_subpos[3 * t + 0] = wx;
                out_subpos[3 * t + 1] = wy;
                out_subpos[3 * t + 2] = wz;
                out_subbatch[t] = (float)batch[i2];
            }
        }
        __syncthreads();
        sx = selp.x; sy = selp.y; sz = selp.z;
        // update min_d with the new point; recompute local (max, argmax)
        lmax = -1.0f; lidx = 0;
        #pragma unroll
        for (int c = 0; c < 16; ++c) {
            float4 o = *reinterpret_cast<const float4*>(&md[c * 2048 + (tid << 2)]);
            float4 nv; bool chg = false;
            #pragma unroll
            for (int e = 0; e < 4; ++e) {
                int j = (c << 2) | e;
                int i = c * 2048 + (tid << 2) + e;
                float dx = lx[j] - sx;
                float dy = ly[j] - sy;
                float dz = lz[j] - sz;
                float xx = dx * dx;
                float yy = dy * dy;
                float zz = dz * dz;
                float d = (xx + yy) + zz;
                float old = (&o.x)[e];
                float nm = fminf(old, d);
                (&nv.x)[e] = nm;
                chg |= (nm < old);
                if (nm > lmax) { lmax = nm; lidx = i; }
            }
            if (chg) *reinterpret_cast<float4*>(&md[c * 2048 + (tid << 2)]) = nv;
        }
    }
}

// ---------------------------------------------------------------------------
// 2) GEMM h = x@W + b (f32 vector ALU) + fused per-block column sum / sumsq.
//    Block: 256 threads -> 64 rows x 128 cols; thread = 8 rows x 4 cols.
__global__ __launch_bounds__(256) void gemm_stats_kernel(
    const float* __restrict__ x, const float* __restrict__ W, const float* __restrict__ bias,
    float* __restrict__ h, float* __restrict__ psum, float* __restrict__ psumsq) {
    __shared__ __align__(16) float Wl[64 * 128];   // 32 KiB  Wl[k*128+c]
    __shared__ float xl[64 * 64];                  // 16 KiB  xl[r*64+k]
    __shared__ float st[8 * 128 * 2];              // 8 KiB

    const int t = threadIdx.x;
    const int r0 = blockIdx.x * 64;
    #pragma unroll
    for (int u = 0; u < 32; ++u) Wl[u * 256 + t] = W[u * 256 + t];
    #pragma unroll
    for (int u = 0; u < 16; ++u) { int f = u * 256 + t; xl[f] = x[r0 * 64 + f]; }
    __syncthreads();

    const int cg = t & 31;   // cols cg*4 .. cg*4+3
    const int rg = t >> 5;   // rows rg*8 .. rg*8+7
    float acc[8][4];
    #pragma unroll
    for (int j = 0; j < 8; ++j)
        #pragma unroll
        for (int cc = 0; cc < 4; ++cc) acc[j][cc] = 0.0f;

    #pragma unroll 4
    for (int k = 0; k < 64; ++k) {
        float4 w4 = *reinterpret_cast<const float4*>(&Wl[k * 128 + cg * 4]);
        #pragma unroll
        for (int j = 0; j < 8; ++j) {
            float xv = xl[(rg * 8 + j) * 64 + k];
            acc[j][0] = fmaf(xv, w4.x, acc[j][0]);
            acc[j][1] = fmaf(xv, w4.y, acc[j][1]);
            acc[j][2] = fmaf(xv, w4.z, acc[j][2]);
            acc[j][3] = fmaf(xv, w4.w, acc[j][3]);
        }
    }
    float4 b4 = *reinterpret_cast<const float4*>(&bias[cg * 4]);
    float s1[4] = {0, 0, 0, 0}, s2[4] = {0, 0, 0, 0};
    #pragma unroll
    for (int j = 0; j < 8; ++j) {
        float4 hv;
        hv.x = acc[j][0] + b4.x;
        hv.y = acc[j][1] + b4.y;
        hv.z = acc[j][2] + b4.z;
        hv.w = acc[j][3] + b4.w;
        *reinterpret_cast<float4*>(&h[(r0 + rg * 8 + j) * 128 + cg * 4]) = hv;
        s1[0] += hv.x; s2[0] += hv.x * hv.x;
        s1[1] += hv.y; s2[1] += hv.y * hv.y;
        s1[2] += hv.z; s2[2] += hv.z * hv.z;
        s1[3] += hv.w; s2[3] += hv.w * hv.w;
    }
    #pragma unroll
    for (int cc = 0; cc < 4; ++cc) {
        st[(rg * 128 + cg * 4 + cc) * 2 + 0] = s1[cc];
        st[(rg * 128 + cg * 4 + cc) * 2 + 1] = s2[cc];
    }
    __syncthreads();
    if (t < 128) {
        float a = 0.0f, q = 0.0f;
        #pragma unroll
        for (int g = 0; g < 8; ++g) {
            a += st[(g * 128 + t) * 2 + 0];
            q += st[(g * 128 + t) * 2 + 1];
        }
        psum[blockIdx.x * 128 + t] = a;
        psumsq[blockIdx.x * 128 + t] = q;
    }
}

// ---------------------------------------------------------------------------
// 3) Finalize BN: fold gamma/beta into per-channel scale/shift. Deterministic.
__global__ void bn_finalize_kernel(const float* __restrict__ psum, const float* __restrict__ psumsq,
                                   const float* __restrict__ gamma, const float* __restrict__ beta,
                                   float* __restrict__ scale, float* __restrict__ shift) {
    int c = threadIdx.x;  // 128 threads
    float s = 0.0f, q = 0.0f;
    #pragma unroll 8
    for (int p = 0; p < 512; ++p) {
        s += psum[p * 128 + c];
        q += psumsq[p * 128 + c];
    }
    float mean = s * (1.0f / N_PTS);
    float var = q * (1.0f / N_PTS) - mean * mean;
    float sc = gamma[c] * rsqrtf(var + BN_EPS_C);
    scale[c] = sc;
    shift[c] = beta[c] - mean * sc;
}

// ---------------------------------------------------------------------------
// 4) kNN: one wave per query; per-lane top-16 by lexicographic (d, idx)
//    (matches stable top_k tie semantics); wave shuffle merge, 16 rounds.
//    Direct (q-p)^2 formula: ~1e-7 error vs the np-f64 arbiter, far inside
//    the rank-16/17 margins that already tolerate jax's 1e-5 expansion error.
__global__ __launch_bounds__(256) void knn_kernel(
    const float* __restrict__ posx, const float* __restrict__ posy, const float* __restrict__ posz,
    const int* __restrict__ ids, int* __restrict__ nn) {
    const int lane = threadIdx.x & 63;
    const int q = blockIdx.x * 4 + (threadIdx.x >> 6);
    const int qi = ids[q];
    const float qx = posx[qi], qy = posy[qi], qz = posz[qi];

    float dv[16]; int di[16];
    #pragma unroll
    for (int j = 0; j < 16; ++j) { dv[j] = FLT_MAX; di[j] = 0x7fffffff; }
    float wm = FLT_MAX; int wmi = 0x7fffffff; int wslot = 0;

    for (int s = 0; s < N_PTS / 64; ++s) {
        int i = s * 64 + lane;
        float dx = posx[i] - qx, dy = posy[i] - qy, dz = posz[i] - qz;
        float d = fmaf(dx, dx, fmaf(dy, dy, dz * dz));
        if (d < wm || (d == wm && i < wmi)) {
            // replace current worst (static indexing only)
            #pragma unroll
            for (int j = 0; j < 16; ++j)
                if (j == wslot) { dv[j] = d; di[j] = i; }
            // recompute worst (lex max)
            wm = -1.0f; wmi = -1;
            #pragma unroll
            for (int j = 0; j < 16; ++j) {
                bool g = (dv[j] > wm) || (dv[j] == wm && di[j] > wmi);
                if (g) { wm = dv[j]; wmi = di[j]; wslot = j; }
            }
        }
    }
    // merge: 16 rounds of wave-wide lex-min
    for (int r = 0; r < 16; ++r) {
        float bv = FLT_MAX; int bidx = 0x7fffffff;
        #pragma unroll
        for (int j = 0; j < 16; ++j) {
            bool g = (dv[j] < bv) || (dv[j] == bv && di[j] < bidx);
            if (g) { bv = dv[j]; bidx = di[j]; }
        }
        #pragma unroll
        for (int off = 32; off; off >>= 1) {
            float ov = __shfl_xor(bv, off);
            int oi = __shfl_xor(bidx, off);
            if (ov < bv || (ov == bv && oi < bidx)) { bv = ov; bidx = oi; }
        }
        if (lane == 0) nn[q * 16 + r] = bidx;
        #pragma unroll
        for (int j = 0; j < 16; ++j)
            if (di[j] == bidx) { dv[j] = FLT_MAX; di[j] = 0x7fffffff; }
    }
}

// ---------------------------------------------------------------------------
// 5) Pool: out[m,c] = relu(max_k (h[nn[m,k],c]*scale[c] + shift[c]))
//    (ReLU commutes with max, monotone; works for any sign of gamma.)
__global__ __launch_bounds__(256) void pool_kernel(
    const float* __restrict__ h, const int* __restrict__ nn,
    const float* __restrict__ scale, const float* __restrict__ shift,
    float* __restrict__ out) {
    const int t = threadIdx.x;
    const int c = t & 127;
    const int m = blockIdx.x * 2 + (t >> 7);
    const float sc = scale[c], sh = shift[c];
    float mx = -FLT_MAX;
    #pragma unroll
    for (int k = 0; k < 16; ++k) {
        int n = nn[m * 16 + k];
        float hv = h[n * 128 + c];
        mx = fmaxf(mx, fmaf(hv, sc, sh));
    }
    out[m * 128 + c] = fmaxf(mx, 0.0f);
}

// ---------------------------------------------------------------------------
extern "C" void kernel_launch(void* const* d_in, const int* in_sizes, int n_in,
                              void* d_out, int out_size, void* d_ws, size_t ws_size,
                              hipStream_t stream) {
    const float* x     = (const float*)d_in[0];  // [N,64]
    const float* pos   = (const float*)d_in[1];  // [N,3]
    const int*   batch = (const int*)d_in[2];    // [N]
    const float* W     = (const float*)d_in[3];  // [64,128]
    const float* b     = (const float*)d_in[4];  // [128]
    const float* gamma = (const float*)d_in[5];  // [128]
    const float* beta  = (const float*)d_in[6];  // [128]
    (void)in_sizes; (void)n_in; (void)out_size; (void)ws_size;

    float* out       = (float*)d_out;                 // [M,128]
    float* sub_pos   = out + (size_t)M_CL * OUT_C;    // [M,3]
    float* sub_batch = sub_pos + (size_t)M_CL * 3;    // [M]

    char* w8 = (char*)d_ws;
    float* posx   = (float*)(w8 + 0);
    float* posy   = (float*)(w8 + 131072);
    float* posz   = (float*)(w8 + 262144);
    int*   ids    = (int*)  (w8 + 393216);
    int*   nn     = (int*)  (w8 + 425984);
    float* psum   = (float*)(w8 + 950272);
    float* psumsq = (float*)(w8 + 1212416);
    float* scale  = (float*)(w8 + 1474560);
    float* shift  = (float*)(w8 + 1475072);
    float* h      = (float*)(w8 + 2097152);

    soa_kernel<<<128, 256, 0, stream>>>(pos, posx, posy, posz);
    fps_kernel<<<1, 512, 0, stream>>>(posx, posy, posz, batch, ids, sub_pos, sub_batch);
    gemm_stats_kernel<<<512, 256, 0, stream>>>(x, W, b, h, psum, psumsq);
    bn_finalize_kernel<<<1, 128, 0, stream>>>(psum, psumsq, gamma, beta, scale, shift);
    knn_kernel<<<2048, 256, 0, stream>>>(posx, posy, posz, ids, nn);
    pool_kernel<<<4096, 256, 0, stream>>>(h, nn, scale, shift, out);
}